// Round 1
// baseline (287.381 us; speedup 1.0000x reference)
//
#include <hip/hip_runtime.h>
#include <stdint.h>

#define NN 4096
#define NITER 10
#define ROWS 16
#define NBLK 256
#define THREADS 1024

// LDS (bytes): KT interleaved [0,131072) | stage 17408 | red 4096 = 152,576
#define STG_OFF  131072
#define RED_OFF  148480

typedef float v2f __attribute__((ext_vector_type(2)));

static __device__ __forceinline__ unsigned short f2bf(float f) {
  union { float f; unsigned int i; } x; x.f = f;
  unsigned int i = x.i;
  i += 0x7FFFu + ((i >> 16) & 1u);
  return (unsigned short)(i >> 16);
}
static __device__ __forceinline__ unsigned int pk2(float a, float b) {
  return (unsigned int)f2bf(a) | ((unsigned int)f2bf(b) << 16);
}
static __device__ __forceinline__ float2 unpk(unsigned int u) {
  union { unsigned int i; float f; } a, b;
  a.i = u << 16; b.i = u & 0xFFFF0000u;
  return make_float2(a.f, b.f);
}
static __device__ __forceinline__ float read_eps(const void* p) {
  float f = *(const float*)p;
  if (f > 1e-4f && f < 1.0f) return f;
  union { unsigned int i; float f; } x;
  x.i = ((unsigned int)*(const unsigned short*)p) << 16;
  return x.f;
}
static __device__ __forceinline__ void astore8(unsigned long long* p, unsigned long long v) {
  __hip_atomic_store(p, v, __ATOMIC_RELAXED, __HIP_MEMORY_SCOPE_AGENT);
}
static __device__ __forceinline__ float4 up4(unsigned int w0, unsigned int w1) {
  float2 a = unpk(w0), b = unpk(w1);
  return make_float4(a.x, a.y, b.x, b.y);
}
static __device__ __forceinline__ v2f mk2(float a, float b) {
  v2f r; r.x = a; r.y = b; return r;
}
#define FMA2(a, b, c) __builtin_elementwise_fma(a, b, c)

// ws poisoned 0xAA pre-launch -> zero flag arrays stream-ordered.
__global__ __launch_bounds__(256) void zero_flags(unsigned int* __restrict__ c) {
#pragma unroll
  for (int k = 0; k < 32; ++k) c[threadIdx.x + k * 256] = 0;   // 8192 uints
}

// Every wave polls the 64 producer flags of one quarter (1 flag/lane).
static __device__ __forceinline__ void wait_group(
    const unsigned int* flags, int q, unsigned token) {
  const unsigned int* p = flags + (q * 64 + (threadIdx.x & 63)) * 16;
  for (;;) {
    unsigned v = __hip_atomic_load(p, __ATOMIC_RELAXED,
                                   __HIP_MEMORY_SCOPE_AGENT);
    if (__ballot(v >= token) == 0xFFFFFFFFFFFFFFFFull) break;
    __builtin_amdgcn_s_sleep(1);
  }
}

// ---------------------------------------------------------------------------
// Persistent, 1024 thr/block (4 waves/SIMD = 50% occ ceiling), block b owns
// rows/cols [16*own, +16) with own = ((b&7)<<5)|(b>>3) (XCD-banded).
// Row-K global+private (L2-resident); col-K^T LDS-resident (lane-linear).
// Sync: per-quarter producer-group flags -> pipelined dataflow.
__global__ __launch_bounds__(THREADS, 1) void sinkhorn_all(
    const float* __restrict__ alpha, const float* __restrict__ beta,
    const float* __restrict__ C, const void* __restrict__ epsp,
    unsigned short* __restrict__ K, unsigned long long* __restrict__ u_ep,
    unsigned long long* __restrict__ v_ep, unsigned int* __restrict__ u_flags,
    unsigned int* __restrict__ v_flags, float* __restrict__ out) {
  __shared__ float4 smem4[9536];             // 152,576 B
  char* sm = (char*)smem4;
  const int t = threadIdx.x, b = blockIdx.x;
  const int wave = t >> 6, lane = t & 63;
  const int own = ((b & 7) << 5) | (b >> 3);
  const int base0 = own * ROWS;              // first owned row AND col
  const float eps = read_eps(epsp);
  const float nie = -1.0f / eps;

  // ---- build row-K (global, private): coalesced C row reads (2 rows/pass) --
#pragma unroll 2
  for (int rp = 0; rp < 8; ++rp) {
    const int r = rp * 2 + (t >> 9);
    const float4* Crow = (const float4*)(C + (size_t)(base0 + r) * NN) + (t & 511) * 2;
    float4 c0 = Crow[0], c1 = Crow[1];
    uint4 k0;
    k0.x = pk2(__expf(c0.x * nie), __expf(c0.y * nie));
    k0.y = pk2(__expf(c0.z * nie), __expf(c0.w * nie));
    k0.z = pk2(__expf(c1.x * nie), __expf(c1.y * nie));
    k0.w = pk2(__expf(c1.z * nie), __expf(c1.w * nie));
    ((uint4*)(K + (size_t)(base0 + r) * NN))[t & 511] = k0;
  }

  // ---- build K^T strip in LDS (lane-linear interleave) ----
  {
    const int p = t & 3, cb = p * 4, rb = t >> 2;   // rb 0..255
#pragma unroll 1
    for (int q2 = 0; q2 < 16; q2 += 8) {
      float4 cv[8];
#pragma unroll
      for (int z = 0; z < 8; ++z)
        cv[z] = *(const float4*)(C + (size_t)((q2 + z) * 256 + rb) * NN + base0 + cb);
#pragma unroll
      for (int z = 0; z < 8; ++z) {
        int n = (q2 + z) * 256 + rb;
        int u16 = ((n >> 10) * 8 + ((n >> 3) & 7)) * 256 + ((n >> 6) & 15) * 16;
        int jo = (n & 7) * 2;
        *(unsigned short*)(sm + (size_t)(u16 + cb + 0) * 16 + jo) = f2bf(__expf(cv[z].x * nie));
        *(unsigned short*)(sm + (size_t)(u16 + cb + 1) * 16 + jo) = f2bf(__expf(cv[z].y * nie));
        *(unsigned short*)(sm + (size_t)(u16 + cb + 2) * 16 + jo) = f2bf(__expf(cv[z].z * nie));
        *(unsigned short*)(sm + (size_t)(u16 + cb + 3) * 16 + jo) = f2bf(__expf(cv[z].w * nie));
      }
    }
  }
  __syncthreads();

  for (int it = 0; it < NITER; ++it) {
    // ========== phase A: u[n] = alpha[n]/(K v)[n], own 16 rows ==========
    // wave handles 1 row; staging transposed: slot(m') = (m'&7)*128+(m'>>3)
    v2f acc01 = {}, acc23 = {};
    const int r0 = base0 + wave;
    const uint4* Kr0 = (const uint4*)(K + (size_t)r0 * NN);
    const uint4* VB = (const uint4*)(v_ep + (size_t)(it - 1) * NN);
#pragma unroll 1
    for (int q = 0; q < 4; ++q) {
      if (it > 0) wait_group(v_flags, q, (unsigned)it);   // per-wave poll
      // prefetch K fragments (L2) before the staging barrier: latency hides
      // under stage+barrier, drained by the barrier's waitcnt.
      uint4 karr[2];
      karr[0] = Kr0[q * 128 + lane];
      karr[1] = Kr0[q * 128 + 64 + lane];
      if (t < 512) {
        float4* L = (float4*)(sm + STG_OFF);
        int s0 = t * 2;
        float4 f0, f1;
        if (it == 0) {
          f0 = f1 = make_float4(1.f, 1.f, 1.f, 1.f);
        } else {
          uint4 sv = VB[q * 512 + t];
          f0 = up4(sv.x, sv.y);
          f1 = up4(sv.z, sv.w);
        }
        L[((s0 & 7) * 128) + (s0 >> 3)] = f0;
        L[(((s0 + 1) & 7) * 128) + ((s0 + 1) >> 3)] = f1;
      }
      __syncthreads();
      const float4* VL = (const float4*)(sm + STG_OFF);
#pragma unroll
      for (int ms = 0; ms < 2; ++ms) {
        int lb = ms * 64 + lane;
        float4 vv[8];
#pragma unroll
        for (int j = 0; j < 8; ++j) vv[j] = VL[j * 128 + lb];  // lane-linear
        unsigned int cw[4] = {karr[ms].x, karr[ms].y, karr[ms].z, karr[ms].w};
#pragma unroll
        for (int w = 0; w < 4; ++w) {
          float2 f = unpk(cw[w]);
          float4 va = vv[2 * w], vb = vv[2 * w + 1];
          acc01 = FMA2(mk2(f.x, f.x), mk2(va.x, va.y), acc01);
          acc23 = FMA2(mk2(f.x, f.x), mk2(va.z, va.w), acc23);
          acc01 = FMA2(mk2(f.y, f.y), mk2(vb.x, vb.y), acc01);
          acc23 = FMA2(mk2(f.y, f.y), mk2(vb.z, vb.w), acc23);
        }
      }
      __syncthreads();
    }
    {
      float accf[4] = {acc01.x, acc01.y, acc23.x, acc23.y};
#pragma unroll
      for (int off = 32; off > 0; off >>= 1)
#pragma unroll
        for (int s = 0; s < 4; ++s)
          accf[s] += __shfl_xor(accf[s], off);
      if (lane == 0) {
        int row = r0;
        float ux = alpha[0 * NN + row] / accf[0];
        float uy = alpha[1 * NN + row] / accf[1];
        float uz = alpha[2 * NN + row] / accf[2];
        float uw = alpha[3 * NN + row] / accf[3];
        unsigned long long ub = (unsigned long long)pk2(ux, uy) |
                                ((unsigned long long)pk2(uz, uw) << 32);
        astore8(u_ep + (size_t)it * NN + row, ub);
        if (it == NITER - 1) {
          out[0 * NN + row] = eps * __logf(ux);
          out[1 * NN + row] = eps * __logf(uy);
          out[2 * NN + row] = eps * __logf(uz);
          out[3 * NN + row] = eps * __logf(uw);
        }
      }
    }
    __syncthreads();   // all u stores drained (vmcnt) before flag publish
    if (t == 0)
      __hip_atomic_store(u_flags + own * 16, (unsigned)(it + 1),
                         __ATOMIC_RELAXED, __HIP_MEMORY_SCOPE_AGENT);

    // ========== phase B: v[m] = beta[m]/(K^T u)[m], own 16 cols ==========
    v2f bacc01 = {}, bacc23 = {};
    const int c = t & 15, k2 = (t >> 4) & 15, half = t >> 8;  // half 0..3
    const uint4* UB = (const uint4*)(u_ep + (size_t)it * NN);
#pragma unroll 1
    for (int q = 0; q < 4; ++q) {
      wait_group(u_flags, q, (unsigned)(it + 1));   // per-wave poll
      // prefetch KT fragments (persistent LDS region, no hazard) pre-barrier
      uint4 kt[2];
#pragma unroll
      for (int i = 0; i < 2; ++i)
        kt[i] = ((const uint4*)sm)[(q * 8 + half * 2 + i) * 256 + k2 * 16 + c];
      if (t < 512) {
        char* US = sm + STG_OFF;
        uint4 su = UB[q * 512 + t];
        float4 f0 = up4(su.x, su.y), f1 = up4(su.z, su.w);
        int n0 = t * 2;                 // pad every 16 slots -> 2-way max
        *(float4*)(US + (n0 + 0) * 16 + ((n0 + 0) >> 4) * 16) = f0;
        *(float4*)(US + (n0 + 1) * 16 + ((n0 + 1) >> 4) * 16) = f1;
      }
      __syncthreads();
      const char* US = sm + STG_OFF;
#pragma unroll
      for (int i = 0; i < 2; ++i) {
        int nb = k2 * 64 + (half * 2 + i) * 8;
        unsigned int kw[4] = {kt[i].x, kt[i].y, kt[i].z, kt[i].w};
#pragma unroll
        for (int w = 0; w < 4; ++w) {
          float2 f = unpk(kw[w]);
          int j0 = nb + 2 * w, j1 = nb + 2 * w + 1;
          float4 u0 = *(const float4*)(US + j0 * 16 + (j0 >> 4) * 16);
          float4 u1 = *(const float4*)(US + j1 * 16 + (j1 >> 4) * 16);
          bacc01 = FMA2(mk2(f.x, f.x), mk2(u0.x, u0.y), bacc01);
          bacc23 = FMA2(mk2(f.x, f.x), mk2(u0.z, u0.w), bacc23);
          bacc01 = FMA2(mk2(f.y, f.y), mk2(u1.x, u1.y), bacc01);
          bacc23 = FMA2(mk2(f.y, f.y), mk2(u1.z, u1.w), bacc23);
        }
      }
      __syncthreads();
    }
    // in-wave pre-reduction: lanes xor 16/32 share the same column c
    {
      float bf[4] = {bacc01.x, bacc01.y, bacc23.x, bacc23.y};
#pragma unroll
      for (int s = 0; s < 4; ++s) {
        bf[s] += __shfl_xor(bf[s], 16);
        bf[s] += __shfl_xor(bf[s], 32);
      }
      if (lane < 16) {
        float4* red = (float4*)(sm + RED_OFF);
        red[wave * 16 + lane] = make_float4(bf[0], bf[1], bf[2], bf[3]);
      }
    }
    __syncthreads();
    if (t < 16) {
      const float4* red = (const float4*)(sm + RED_OFF);
      float4 a = make_float4(0.f, 0.f, 0.f, 0.f);
#pragma unroll
      for (int g = 0; g < 16; ++g) {
        float4 r = red[g * 16 + t];
        a.x += r.x; a.y += r.y; a.z += r.z; a.w += r.w;
      }
      int m = base0 + t;
      float vx = beta[0 * NN + m] / a.x;
      float vy = beta[1 * NN + m] / a.y;
      float vz = beta[2 * NN + m] / a.z;
      float vw = beta[3 * NN + m] / a.w;
      unsigned long long vb = (unsigned long long)pk2(vx, vy) |
                              ((unsigned long long)pk2(vz, vw) << 32);
      astore8(v_ep + (size_t)it * NN + m, vb);
      if (it == NITER - 1) {
        out[4 * NN + 0 * NN + m] = eps * __logf(vx);
        out[4 * NN + 1 * NN + m] = eps * __logf(vy);
        out[4 * NN + 2 * NN + m] = eps * __logf(vz);
        out[4 * NN + 3 * NN + m] = eps * __logf(vw);
      }
    }
    __syncthreads();   // v stores drained before flag publish + LDS reuse
    if (t == 0 && it < NITER - 1)
      __hip_atomic_store(v_flags + own * 16, (unsigned)(it + 1),
                         __ATOMIC_RELAXED, __HIP_MEMORY_SCOPE_AGENT);
  }
}

// ---------------------------------------------------------------------------
extern "C" void kernel_launch(void* const* d_in, const int* in_sizes, int n_in,
                              void* d_out, int out_size, void* d_ws, size_t ws_size,
                              hipStream_t stream) {
  (void)in_sizes; (void)n_in; (void)out_size; (void)ws_size;
  const float* alpha = (const float*)d_in[0];   // f32 (4,4096)
  const float* beta  = (const float*)d_in[1];   // f32 (4,4096)
  const float* C     = (const float*)d_in[2];   // f32 (4096,4096)
  const void*  epsp  = d_in[3];                 // f32 scalar

  char* ws = (char*)d_ws;
  unsigned short* K        = (unsigned short*)ws;                   // 32 MiB
  unsigned long long* u_ep = (unsigned long long*)(ws + 33554432);  // 320 KiB
  unsigned long long* v_ep = (unsigned long long*)(ws + 33554432 + 327680);
  unsigned int* u_flags    = (unsigned int*)(ws + 33554432 + 655360);  // 16 KiB
  unsigned int* v_flags    = (unsigned int*)(ws + 33554432 + 655360 + 16384);
  float* out = (float*)d_out;

  zero_flags<<<1, 256, 0, stream>>>(u_flags);   // zeros u_flags + v_flags
  sinkhorn_all<<<NBLK, THREADS, 0, stream>>>(alpha, beta, C, epsp, K,
                                             u_ep, v_ep, u_flags, v_flags, out);
}

// Round 3
// 286.766 us; speedup vs baseline: 1.0021x; 1.0021x over previous
//
#include <hip/hip_runtime.h>
#include <stdint.h>

#define NN 4096
#define NITER 10
#define ROWS 16
#define NBLK 256
#define THREADS 512

// LDS (bytes): KT interleaved [0,131072) | stage 2x8192 | red 2048 = 149,504
#define STG_OFF  131072
#define RED_OFF  147456
// bank swizzle for 16B staging slots: spread bank-group by slot>>3
#define SWZ(s) ((((unsigned)(s)) * 16u) ^ ((((unsigned)(s)) >> 3 & 7u) << 4))

typedef float v2f __attribute__((ext_vector_type(2)));

static __device__ __forceinline__ unsigned short f2bf(float f) {
  union { float f; unsigned int i; } x; x.f = f;
  unsigned int i = x.i;
  i += 0x7FFFu + ((i >> 16) & 1u);
  return (unsigned short)(i >> 16);
}
static __device__ __forceinline__ unsigned int pk2(float a, float b) {
  return (unsigned int)f2bf(a) | ((unsigned int)f2bf(b) << 16);
}
static __device__ __forceinline__ float2 unpk(unsigned int u) {
  union { unsigned int i; float f; } a, b;
  a.i = u << 16; b.i = u & 0xFFFF0000u;
  return make_float2(a.f, b.f);
}
static __device__ __forceinline__ float read_eps(const void* p) {
  float f = *(const float*)p;
  if (f > 1e-4f && f < 1.0f) return f;
  union { unsigned int i; float f; } x;
  x.i = ((unsigned int)*(const unsigned short*)p) << 16;
  return x.f;
}
static __device__ __forceinline__ void astore8(unsigned long long* p, unsigned long long v) {
  __hip_atomic_store(p, v, __ATOMIC_RELAXED, __HIP_MEMORY_SCOPE_AGENT);
}
static __device__ __forceinline__ v2f mk2(float a, float b) {
  v2f r; r.x = a; r.y = b; return r;
}
#define FMA2(a, b, c) __builtin_elementwise_fma(a, b, c)

// ws poisoned 0xAA pre-launch -> zero flag arrays stream-ordered.
__global__ __launch_bounds__(256) void zero_flags(unsigned int* __restrict__ c) {
#pragma unroll
  for (int k = 0; k < 32; ++k) c[threadIdx.x + k * 256] = 0;   // 8192 uints
}

// Wait for ALL 256 producer flags >= token. Bounded spin (~0.1 s worst case,
// >>1000x any legitimate wait): a deadlock terminates with wrong results
// (diagnosable absmax) instead of hanging the container.
static __device__ __forceinline__ void wait_all(
    const unsigned int* flags, unsigned token) {
  const unsigned int* p = flags + (threadIdx.x & 63) * 16;
  for (int spin = 0; spin < 200000; ++spin) {
    unsigned a = __hip_atomic_load(p, __ATOMIC_RELAXED, __HIP_MEMORY_SCOPE_AGENT);
    unsigned b = __hip_atomic_load(p + 64 * 16, __ATOMIC_RELAXED, __HIP_MEMORY_SCOPE_AGENT);
    unsigned c = __hip_atomic_load(p + 128 * 16, __ATOMIC_RELAXED, __HIP_MEMORY_SCOPE_AGENT);
    unsigned d = __hip_atomic_load(p + 192 * 16, __ATOMIC_RELAXED, __HIP_MEMORY_SCOPE_AGENT);
    unsigned mn = min(min(a, b), min(c, d));
    if (__ballot(mn >= token) == 0xFFFFFFFFFFFFFFFFull) break;
    __builtin_amdgcn_s_sleep(1);
  }
}

// ---------------------------------------------------------------------------
// Persistent, 512 thr/block (R1 showed occupancy is not the limiter), block b
// owns rows/cols [16*own, +16) with own = ((b&7)<<5)|(b>>3) (XCD-banded).
// Row-K global+private (L2-resident); col-K^T LDS-resident (lane-linear).
// Staging: raw bf16 (half the LDS bytes), XOR-swizzled slots, double-buffered
// with loads issued before compute and ds_writes after (latency hidden).
// Sync: one wait-all poll per phase; one barrier per quarter.
__global__ __launch_bounds__(THREADS, 1) void sinkhorn_all(
    const float* __restrict__ alpha, const float* __restrict__ beta,
    const float* __restrict__ C, const void* __restrict__ epsp,
    unsigned short* __restrict__ K, unsigned long long* __restrict__ u_ep,
    unsigned long long* __restrict__ v_ep, unsigned int* __restrict__ u_flags,
    unsigned int* __restrict__ v_flags, float* __restrict__ out) {
  __shared__ float4 smem4[9344];             // 149,504 B
  char* sm = (char*)smem4;
  const int t = threadIdx.x, b = blockIdx.x;
  const int wave = t >> 6, lane = t & 63;
  const int own = ((b & 7) << 5) | (b >> 3);
  const int base0 = own * ROWS;              // first owned row AND col
  const float eps = read_eps(epsp);
  const float nie = -1.0f / eps;

  // ---- build row-K (global, private): coalesced C row reads ----
#pragma unroll 2
  for (int r = 0; r < ROWS; ++r) {
    const float4* Crow = (const float4*)(C + (size_t)(base0 + r) * NN) + t * 2;
    float4 c0 = Crow[0], c1 = Crow[1];
    uint4 k0;
    k0.x = pk2(__expf(c0.x * nie), __expf(c0.y * nie));
    k0.y = pk2(__expf(c0.z * nie), __expf(c0.w * nie));
    k0.z = pk2(__expf(c1.x * nie), __expf(c1.y * nie));
    k0.w = pk2(__expf(c1.z * nie), __expf(c1.w * nie));
    ((uint4*)(K + (size_t)(base0 + r) * NN))[t] = k0;
  }

  // ---- build K^T strip in LDS (lane-linear interleave) ----
  {
    const int p = t & 3, cb = p * 4, rb = t >> 2;   // rb 0..127
#pragma unroll 1
    for (int q2 = 0; q2 < 32; q2 += 8) {
      float4 cv[8];
#pragma unroll
      for (int z = 0; z < 8; ++z)
        cv[z] = *(const float4*)(C + (size_t)((q2 + z) * 128 + rb) * NN + base0 + cb);
#pragma unroll
      for (int z = 0; z < 8; ++z) {
        int n = (q2 + z) * 128 + rb;
        int u16 = ((n >> 10) * 8 + ((n >> 3) & 7)) * 256 + ((n >> 6) & 15) * 16;
        int jo = (n & 7) * 2;
        *(unsigned short*)(sm + (size_t)(u16 + cb + 0) * 16 + jo) = f2bf(__expf(cv[z].x * nie));
        *(unsigned short*)(sm + (size_t)(u16 + cb + 1) * 16 + jo) = f2bf(__expf(cv[z].y * nie));
        *(unsigned short*)(sm + (size_t)(u16 + cb + 2) * 16 + jo) = f2bf(__expf(cv[z].z * nie));
        *(unsigned short*)(sm + (size_t)(u16 + cb + 3) * 16 + jo) = f2bf(__expf(cv[z].w * nie));
      }
    }
  }
  __syncthreads();

  const uint4 ONES = make_uint4(0x3F803F80u, 0x3F803F80u, 0x3F803F80u, 0x3F803F80u);

  for (int it = 0; it < NITER; ++it) {
    // ========== phase A: u[n] = alpha[n]/(K v)[n], own 16 rows ==========
    // wave handles 2 rows; staging slot(pair p) = (p&3)*128 + (p>>2), SWZ'd.
    v2f acc01[2] = {}, acc23[2] = {};
    const int r0 = base0 + wave * 2;
    const uint4* Kr0 = (const uint4*)(K + (size_t)r0 * NN);
    const uint4* VB = (const uint4*)(v_ep + (size_t)(it - 1) * NN);
    if (it > 0) wait_all(v_flags, (unsigned)it);
    {
      uint4 sv = (it == 0) ? ONES : VB[t];
      *(uint4*)(sm + STG_OFF + SWZ((t & 3) * 128 + (t >> 2))) = sv;
    }
    uint4 ka[4];
#pragma unroll
    for (int ms = 0; ms < 2; ++ms) {
      ka[ms * 2 + 0] = Kr0[ms * 64 + lane];
      ka[ms * 2 + 1] = Kr0[512 + ms * 64 + lane];
    }
    __syncthreads();
#pragma unroll 1
    for (int q = 0; q < 4; ++q) {
      uint4 sv_n, ka_n[4];
      if (q < 3) {                       // issue next-quarter loads FIRST
        sv_n = (it == 0) ? ONES : VB[(q + 1) * 512 + t];
#pragma unroll
        for (int ms = 0; ms < 2; ++ms) {
          ka_n[ms * 2 + 0] = Kr0[(q + 1) * 128 + ms * 64 + lane];
          ka_n[ms * 2 + 1] = Kr0[512 + (q + 1) * 128 + ms * 64 + lane];
        }
      }
      const char* stg = sm + STG_OFF + (q & 1) * 8192;
#pragma unroll
      for (int ms = 0; ms < 2; ++ms) {
        const int lb = ms * 64 + lane;
        uint4 vq[4];
#pragma unroll
        for (int jj = 0; jj < 4; ++jj)
          vq[jj] = *(const uint4*)(stg + SWZ(jj * 128 + lb));
        float2 va01[4], va23[4], vb01[4], vb23[4];
#pragma unroll
        for (int w = 0; w < 4; ++w) {
          va01[w] = unpk(vq[w].x); va23[w] = unpk(vq[w].y);
          vb01[w] = unpk(vq[w].z); vb23[w] = unpk(vq[w].w);
        }
#pragma unroll
        for (int rr = 0; rr < 2; ++rr) {
          unsigned int cw[4] = {ka[ms * 2 + rr].x, ka[ms * 2 + rr].y,
                                ka[ms * 2 + rr].z, ka[ms * 2 + rr].w};
#pragma unroll
          for (int w = 0; w < 4; ++w) {
            float2 f = unpk(cw[w]);
            acc01[rr] = FMA2(mk2(f.x, f.x), mk2(va01[w].x, va01[w].y), acc01[rr]);
            acc23[rr] = FMA2(mk2(f.x, f.x), mk2(va23[w].x, va23[w].y), acc23[rr]);
            acc01[rr] = FMA2(mk2(f.y, f.y), mk2(vb01[w].x, vb01[w].y), acc01[rr]);
            acc23[rr] = FMA2(mk2(f.y, f.y), mk2(vb23[w].x, vb23[w].y), acc23[rr]);
          }
        }
      }
      if (q < 3) {                       // write-late: vmcnt drains here
        *(uint4*)(sm + STG_OFF + ((q + 1) & 1) * 8192 +
                  SWZ((t & 3) * 128 + (t >> 2))) = sv_n;
#pragma unroll
        for (int z = 0; z < 4; ++z) ka[z] = ka_n[z];
      }
      __syncthreads();
    }
    {
      float accf[2][4];
#pragma unroll
      for (int rr = 0; rr < 2; ++rr) {
        accf[rr][0] = acc01[rr].x; accf[rr][1] = acc01[rr].y;
        accf[rr][2] = acc23[rr].x; accf[rr][3] = acc23[rr].y;
      }
#pragma unroll
      for (int off = 32; off > 0; off >>= 1)
#pragma unroll
        for (int rr = 0; rr < 2; ++rr)
#pragma unroll
          for (int s = 0; s < 4; ++s)
            accf[rr][s] += __shfl_xor(accf[rr][s], off);
      if (lane < 2) {
        int row = r0 + lane;
        float ux = alpha[0 * NN + row] / accf[lane][0];
        float uy = alpha[1 * NN + row] / accf[lane][1];
        float uz = alpha[2 * NN + row] / accf[lane][2];
        float uw = alpha[3 * NN + row] / accf[lane][3];
        unsigned long long ub = (unsigned long long)pk2(ux, uy) |
                                ((unsigned long long)pk2(uz, uw) << 32);
        astore8(u_ep + (size_t)it * NN + row, ub);
        if (it == NITER - 1) {
          out[0 * NN + row] = eps * __logf(ux);
          out[1 * NN + row] = eps * __logf(uy);
          out[2 * NN + row] = eps * __logf(uz);
          out[3 * NN + row] = eps * __logf(uw);
        }
      }
    }
    __syncthreads();   // all u stores drained (vmcnt) before flag publish
    if (t == 0)
      __hip_atomic_store(u_flags + own * 16, (unsigned)(it + 1),
                         __ATOMIC_RELAXED, __HIP_MEMORY_SCOPE_AGENT);

    // ========== phase B: v[m] = beta[m]/(K^T u)[m], own 16 cols ==========
    // thread handles cols {c, c+8}: u LDS reads reused in-register x2.
    v2f bacc01[2] = {}, bacc23[2] = {};
    const int c = t & 7, k2 = (t >> 3) & 15, half = t >> 7;  // half 0..3
    const uint4* UB = (const uint4*)(u_ep + (size_t)it * NN);
    wait_all(u_flags, (unsigned)(it + 1));
    {
      uint4 su = UB[t];
      *(uint4*)(sm + STG_OFF + SWZ((t & 3) * 128 + (t >> 2))) = su;
    }
    uint4 kt[4];
#pragma unroll
    for (int i = 0; i < 2; ++i) {
      int s = half * 2 + i;
      kt[i * 2 + 0] = ((const uint4*)sm)[(0 * 8 + s) * 256 + k2 * 16 + c];
      kt[i * 2 + 1] = ((const uint4*)sm)[(0 * 8 + s) * 256 + k2 * 16 + c + 8];
    }
    __syncthreads();
#pragma unroll 1
    for (int q = 0; q < 4; ++q) {
      uint4 su_n, kt_n[4];
      if (q < 3) {                       // issue next-quarter loads FIRST
        su_n = UB[(q + 1) * 512 + t];
#pragma unroll
        for (int i = 0; i < 2; ++i) {
          int s = half * 2 + i;
          kt_n[i * 2 + 0] = ((const uint4*)sm)[((q + 1) * 8 + s) * 256 + k2 * 16 + c];
          kt_n[i * 2 + 1] = ((const uint4*)sm)[((q + 1) * 8 + s) * 256 + k2 * 16 + c + 8];
        }
      }
      const char* stg = sm + STG_OFF + (q & 1) * 8192;
#pragma unroll
      for (int i = 0; i < 2; ++i) {
        const int s = half * 2 + i;
        uint4 uq[4];
#pragma unroll
        for (int jj = 0; jj < 4; ++jj)
          uq[jj] = *(const uint4*)(stg + SWZ(jj * 128 + k2 * 8 + s));
        float2 u01[8], u23[8];
#pragma unroll
        for (int jj = 0; jj < 4; ++jj) {
          u01[2 * jj]     = unpk(uq[jj].x); u23[2 * jj]     = unpk(uq[jj].y);
          u01[2 * jj + 1] = unpk(uq[jj].z); u23[2 * jj + 1] = unpk(uq[jj].w);
        }
#pragma unroll
        for (int cs = 0; cs < 2; ++cs) {
          unsigned int kw[4] = {kt[i * 2 + cs].x, kt[i * 2 + cs].y,
                                kt[i * 2 + cs].z, kt[i * 2 + cs].w};
#pragma unroll
          for (int w = 0; w < 4; ++w) {
            float2 f = unpk(kw[w]);
            bacc01[cs] = FMA2(mk2(f.x, f.x), mk2(u01[2 * w].x, u01[2 * w].y), bacc01[cs]);
            bacc23[cs] = FMA2(mk2(f.x, f.x), mk2(u23[2 * w].x, u23[2 * w].y), bacc23[cs]);
            bacc01[cs] = FMA2(mk2(f.y, f.y), mk2(u01[2 * w + 1].x, u01[2 * w + 1].y), bacc01[cs]);
            bacc23[cs] = FMA2(mk2(f.y, f.y), mk2(u23[2 * w + 1].x, u23[2 * w + 1].y), bacc23[cs]);
          }
        }
      }
      if (q < 3) {                       // write-late staging
        *(uint4*)(sm + STG_OFF + ((q + 1) & 1) * 8192 +
                  SWZ((t & 3) * 128 + (t >> 2))) = su_n;
#pragma unroll
        for (int z = 0; z < 4; ++z) kt[z] = kt_n[z];
      }
      __syncthreads();
    }
    // in-wave pre-reduction over k2&7 (lanes xor 8,16,32 share col c)
    {
      float bf0[4] = {bacc01[0].x, bacc01[0].y, bacc23[0].x, bacc23[0].y};
      float bf1[4] = {bacc01[1].x, bacc01[1].y, bacc23[1].x, bacc23[1].y};
#pragma unroll
      for (int off = 8; off <= 32; off <<= 1)
#pragma unroll
        for (int s2 = 0; s2 < 4; ++s2) {
          bf0[s2] += __shfl_xor(bf0[s2], off);
          bf1[s2] += __shfl_xor(bf1[s2], off);
        }
      if (lane < 8) {
        float4* red = (float4*)(sm + RED_OFF);
        red[(wave * 8 + lane) * 2 + 0] = make_float4(bf0[0], bf0[1], bf0[2], bf0[3]);
        red[(wave * 8 + lane) * 2 + 1] = make_float4(bf1[0], bf1[1], bf1[2], bf1[3]);
      }
    }
    __syncthreads();
    if (t < 16) {
      const float4* red = (const float4*)(sm + RED_OFF);
      const int cc = t & 7, sel = t >> 3;
      float4 a = make_float4(0.f, 0.f, 0.f, 0.f);
#pragma unroll
      for (int g = 0; g < 8; ++g) {
        float4 r = red[(g * 8 + cc) * 2 + sel];
        a.x += r.x; a.y += r.y; a.z += r.z; a.w += r.w;
      }
      int m = base0 + t;     // = base0 + sel*8 + cc
      float vx = beta[0 * NN + m] / a.x;
      float vy = beta[1 * NN + m] / a.y;
      float vz = beta[2 * NN + m] / a.z;
      float vw = beta[3 * NN + m] / a.w;
      unsigned long long vb = (unsigned long long)pk2(vx, vy) |
                              ((unsigned long long)pk2(vz, vw) << 32);
      astore8(v_ep + (size_t)it * NN + m, vb);
      if (it == NITER - 1) {
        out[4 * NN + 0 * NN + m] = eps * __logf(vx);
        out[4 * NN + 1 * NN + m] = eps * __logf(vy);
        out[4 * NN + 2 * NN + m] = eps * __logf(vz);
        out[4 * NN + 3 * NN + m] = eps * __logf(vw);
      }
    }
    __syncthreads();   // v stores drained before flag publish + LDS reuse
    if (t == 0 && it < NITER - 1)
      __hip_atomic_store(v_flags + own * 16, (unsigned)(it + 1),
                         __ATOMIC_RELAXED, __HIP_MEMORY_SCOPE_AGENT);
  }
}

// ---------------------------------------------------------------------------
extern "C" void kernel_launch(void* const* d_in, const int* in_sizes, int n_in,
                              void* d_out, int out_size, void* d_ws, size_t ws_size,
                              hipStream_t stream) {
  (void)in_sizes; (void)n_in; (void)out_size; (void)ws_size;
  const float* alpha = (const float*)d_in[0];   // f32 (4,4096)
  const float* beta  = (const float*)d_in[1];   // f32 (4,4096)
  const float* C     = (const float*)d_in[2];   // f32 (4096,4096)
  const void*  epsp  = d_in[3];                 // f32 scalar

  char* ws = (char*)d_ws;
  unsigned short* K        = (unsigned short*)ws;                   // 32 MiB
  unsigned long long* u_ep = (unsigned long long*)(ws + 33554432);  // 320 KiB
  unsigned long long* v_ep = (unsigned long long*)(ws + 33554432 + 327680);
  unsigned int* u_flags    = (unsigned int*)(ws + 33554432 + 655360);  // 16 KiB
  unsigned int* v_flags    = (unsigned int*)(ws + 33554432 + 655360 + 16384);
  float* out = (float*)d_out;

  zero_flags<<<1, 256, 0, stream>>>(u_flags);   // zeros u_flags + v_flags
  sinkhorn_all<<<NBLK, THREADS, 0, stream>>>(alpha, beta, C, epsp, K,
                                             u_ep, v_ep, u_flags, v_flags, out);
}